// Round 12
// baseline (371.510 us; speedup 1.0000x reference)
//
#include <hip/hip_runtime.h>
#include <hip/hip_bf16.h>

#define NTOT 8192
#define FIN 128
#define FOUT 32
#define NH 4
#define NSEG 8
#define SEGJ (NTOT / NSEG)  // 1024

#define LOG2E 1.4426950408889634f

typedef __attribute__((ext_vector_type(4))) float f32x4;
typedef __attribute__((ext_vector_type(4))) int i32x4;
typedef __attribute__((ext_vector_type(4))) unsigned int u32x4;
typedef __attribute__((ext_vector_type(8))) __bf16 bf16x8;
typedef unsigned long long u64;
typedef unsigned int u32;

__device__ __forceinline__ unsigned short f2bf(float x) {
  __hip_bfloat16 h = __float2bfloat16(x);
  return *reinterpret_cast<unsigned short*>(&h);
}

__device__ __forceinline__ float fexp2(float y) {
  float p;
  asm("v_exp_f32 %0, %1" : "=v"(p) : "v"(y));
  return p;
}

// ---------------- k1: h = X @ W -> h [N][128] f32, plus B-fragment panels:
// panel[(p*256 + jt)*512 + l*8 + e] (bf16), p = hd*2+half,
//   value = h[node = jt*32 + (l>>4)*8 + e][p*16 + (l&15)]
__global__ __launch_bounds__(256, 2) void k1_project(
    const float* __restrict__ X, const float* __restrict__ W,
    float* __restrict__ h, unsigned short* __restrict__ panel) {
  __shared__ float Xs[32 * 128];
  __shared__ float Ws[32 * 128];
  __shared__ unsigned short Hs[128 * 40];  // [o][node_local], stride 40
  int t = threadIdx.x;
  int nb = blockIdx.x * 32;

  const f32x4* Xg = reinterpret_cast<const f32x4*>(X + (size_t)nb * FIN);
  f32x4* Xs4 = reinterpret_cast<f32x4*>(Xs);
#pragma unroll
  for (int r = 0; r < 4; ++r) Xs4[t + r * 256] = Xg[t + r * 256];

  int ng = t >> 5, oq = t & 31;
  int n0 = ng * 4, o0 = oq * 4;
  f32x4 acc[4];
#pragma unroll
  for (int nn = 0; nn < 4; ++nn) acc[nn] = (f32x4){0.f, 0.f, 0.f, 0.f};

  for (int kp = 0; kp < 4; ++kp) {
    __syncthreads();
#pragma unroll
    for (int r = 0; r < 4; ++r) {
      int q = t + r * 256;
      int flat = q * 4;
      int kk = flat >> 7;
      int c = flat & 127;
      int hdd = c >> 5;
      int oo = c & 31;
      *reinterpret_cast<f32x4*>(&Ws[kk * 128 + c]) =
          *reinterpret_cast<const f32x4*>(W + hdd * (FIN * FOUT) +
                                          (kp * 32 + kk) * FOUT + oo);
    }
    __syncthreads();
#pragma unroll 8
    for (int kk = 0; kk < 32; ++kk) {
      f32x4 wv = *reinterpret_cast<const f32x4*>(&Ws[kk * 128 + o0]);
#pragma unroll
      for (int nn = 0; nn < 4; ++nn)
        acc[nn] += Xs[(n0 + nn) * 128 + kp * 32 + kk] * wv;
    }
  }
#pragma unroll
  for (int nn = 0; nn < 4; ++nn) {
    *reinterpret_cast<f32x4*>(&h[(size_t)(nb + n0 + nn) * 128 + o0]) = acc[nn];
#pragma unroll
    for (int c = 0; c < 4; ++c)
      Hs[(o0 + c) * 40 + (n0 + nn)] = f2bf(acc[nn][c]);
  }
  __syncthreads();
  int jt = blockIdx.x;
#pragma unroll
  for (int it = 0; it < 2; ++it) {
    int item = t + it * 256;
    int p = item >> 6;
    int l = item & 63;
    int o = p * 16 + (l & 15);
    u32x4 v = *reinterpret_cast<const u32x4*>(&Hs[o * 40 + (l >> 4) * 8]);
    *reinterpret_cast<u32x4*>(panel + (size_t)(p * 256 + jt) * 512 + l * 8) = v;
  }
}

// ---------------- k2: per-node scores (x log2e). Sl2 [hd][N]; Dt [jm][hd][64]
__global__ __launch_bounds__(256, 2) void k2_scores(
    const float* __restrict__ h, const float* __restrict__ a_src,
    const float* __restrict__ a_dst, float* __restrict__ Sl2,
    float* __restrict__ Dt) {
  int n = blockIdx.x * 256 + threadIdx.x;
  const f32x4* hv = reinterpret_cast<const f32x4*>(h + (size_t)n * 128);
  const f32x4* as4 = reinterpret_cast<const f32x4*>(a_src);
  const f32x4* ad4 = reinterpret_cast<const f32x4*>(a_dst);
#pragma unroll
  for (int hd = 0; hd < NH; ++hd) {
    f32x4 sa = {0.f, 0.f, 0.f, 0.f}, da = {0.f, 0.f, 0.f, 0.f};
#pragma unroll
    for (int q = 0; q < 8; ++q) {
      f32x4 x = hv[hd * 8 + q];
      sa += x * as4[hd * 8 + q];
      da += x * ad4[hd * 8 + q];
    }
    float s = (sa[0] + sa[1]) + (sa[2] + sa[3]);
    float d = (da[0] + da[1]) + (da[2] + da[3]);
    Sl2[hd * NTOT + n] = s * LOG2E;
    Dt[(n >> 6) * 256 + hd * 64 + (n & 63)] = d * LOG2E;
  }
}

// ---------------- k3: fused adj-read + masked softmax + PV.
// 4 waves/block; wave w = rows [ibase+w*16, +16) x ALL 4 heads (adj read once).
// NSEG=8 split-j -> 4096 waves = 4 waves/SIMD (occupancy was the R11 limiter).
__global__ __launch_bounds__(256, 4) void k3_attn(
    const int* __restrict__ adj, const float* __restrict__ Sl2,
    const float* __restrict__ Dt, const unsigned short* __restrict__ panel,
    float* __restrict__ pacc, float* __restrict__ plsum) {
  const int N = NTOT;
  int tid = threadIdx.x;
  int w = tid >> 6, l = tid & 63;
  int itile = blockIdx.x >> 3, seg = blockIdx.x & 7;
  int ibase = itile * 64;
  int m = l & 15, g = l >> 4, jc = g * 8;
  int row = ibase + w * 16 + m;
  int seg0 = seg * (SEGJ / 64);  // first 64-j macro of this segment (16/seg)

  float svv[4];
#pragma unroll
  for (int hd = 0; hd < 4; ++hd) svv[hd] = Sl2[hd * N + row];

  const int* adjr = adj + (size_t)row * N + seg * SEGJ + jc;

  f32x4 z4 = {0.f, 0.f, 0.f, 0.f};
  f32x4 c0[4] = {z4, z4, z4, z4}, c1[4] = {z4, z4, z4, z4},
        cs[4] = {z4, z4, z4, z4};
  bf16x8 bones;
  {
    u32 pat = (m == 0) ? 0x3f803f80u : 0u;
    u32x4 tmp = {pat, pat, pat, pat};
    bones = *reinterpret_cast<bf16x8*>(&tmp);
  }

  i32x4 Aa0, Aa1, Aa2, Aa3, Ba0, Ba1, Ba2, Ba3;

  // adj prefetch for macro t_ (pinned so it cannot be sunk)
#define AISS(P, t_)                                            \
  {                                                            \
    int tc_ = (t_) > 15 ? 15 : (t_);                           \
    const int* a_ = adjr + tc_ * 64;                           \
    P##a0 = *reinterpret_cast<const i32x4*>(a_);               \
    P##a1 = *reinterpret_cast<const i32x4*>(a_ + 4);           \
    P##a2 = *reinterpret_cast<const i32x4*>(a_ + 32);          \
    P##a3 = *reinterpret_cast<const i32x4*>(a_ + 36);          \
  }                                                            \
  __builtin_amdgcn_sched_barrier(0);

  // masked A-frag: y = LeakyReLU(s+d)*log2e, gated to -1e9 by adj, exp2
#define AFSEL(AF, AV0, AV1, DA, DB, SV)                                  \
  {                                                                      \
    f32x4 xa_ = (DA) + (SV);                                             \
    f32x4 xb_ = (DB) + (SV);                                             \
    f32x4 ya_ = __builtin_elementwise_max(xa_, 0.2f * xa_);              \
    f32x4 yb_ = __builtin_elementwise_max(xb_, 0.2f * xb_);              \
    _Pragma("unroll") for (int e = 0; e < 4; ++e) {                      \
      float y_ = ((AV0)[e] != 0) ? ya_[e] : -1e9f;                       \
      AF[e] = (__bf16)fexp2(y_);                                         \
    }                                                                    \
    _Pragma("unroll") for (int e = 0; e < 4; ++e) {                      \
      float y_ = ((AV1)[e] != 0) ? yb_[e] : -1e9f;                       \
      AF[e + 4] = (__bf16)fexp2(y_);                                     \
    }                                                                    \
  }

#define MFM(AF, B, ACC) \
  ACC = __builtin_amdgcn_mfma_f32_16x16x32_bf16(AF, B, ACC, 0, 0, 0);

  // full macro: 4 heads x (2 k-halves x 3 MFMA)
#define MATHM(P, t_)                                                      \
  {                                                                       \
    int jm_ = seg0 + (t_);                                                \
    const float* db_ = Dt + (size_t)jm_ * 256;                            \
    const unsigned short* pb_ =                                           \
        panel + (size_t)(seg * (SEGJ / 32) + (t_)*2) * 512 + l * 8;       \
    _Pragma("unroll") for (int hd = 0; hd < 4; ++hd) {                    \
      f32x4 d0 = *(const f32x4*)(db_ + hd * 64 + jc);                     \
      f32x4 d1 = *(const f32x4*)(db_ + hd * 64 + jc + 4);                 \
      f32x4 d2 = *(const f32x4*)(db_ + hd * 64 + 32 + jc);                \
      f32x4 d3 = *(const f32x4*)(db_ + hd * 64 + 32 + jc + 4);            \
      const unsigned short* p0_ = pb_ + (size_t)(hd * 2) * 131072;        \
      const unsigned short* p1_ = pb_ + (size_t)(hd * 2 + 1) * 131072;    \
      bf16x8 B0a = *(const bf16x8*)(p0_);                                 \
      bf16x8 B1a = *(const bf16x8*)(p1_);                                 \
      bf16x8 B0b = *(const bf16x8*)(p0_ + 512);                           \
      bf16x8 B1b = *(const bf16x8*)(p1_ + 512);                           \
      float sv_ = svv[hd];                                                \
      bf16x8 af_;                                                         \
      AFSEL(af_, P##a0, P##a1, d0, d1, sv_)                               \
      MFM(af_, B0a, c0[hd]) MFM(af_, B1a, c1[hd]) MFM(af_, bones, cs[hd]) \
      AFSEL(af_, P##a2, P##a3, d2, d3, sv_)                               \
      MFM(af_, B0b, c0[hd]) MFM(af_, B1b, c1[hd]) MFM(af_, bones, cs[hd]) \
    }                                                                     \
  }

  AISS(A, 0)
  AISS(B, 1)
#pragma unroll 1
  for (int tt = 0; tt < 8; ++tt) {
    MATHM(A, 2 * tt)
    AISS(A, 2 * tt + 2)
    MATHM(B, 2 * tt + 1)
    AISS(B, 2 * tt + 3)
  }
#undef AISS
#undef AFSEL
#undef MFM
#undef MATHM

  // epilogue: D layout col=lane&15 (o), row=(lane>>4)*4+reg (i)
#pragma unroll
  for (int hd = 0; hd < 4; ++hd) {
    int rb = ibase + w * 16 + g * 4;
    if (m == 0) {
#pragma unroll
      for (int r = 0; r < 4; ++r)
        plsum[(seg * NH + hd) * N + rb + r] = cs[hd][r];
    }
#pragma unroll
    for (int r = 0; r < 4; ++r) {
      int rowr = rb + r;
      pacc[((size_t)seg * N + rowr) * 128 + hd * 32 + m] = c0[hd][r];
      pacc[((size_t)seg * N + rowr) * 128 + hd * 32 + 16 + m] = c1[hd][r];
    }
  }
}

// ---------------- k4: combine segments + normalize
__global__ __launch_bounds__(256, 2) void k4_combine(
    const float* __restrict__ pacc, const float* __restrict__ plsum,
    float* __restrict__ out) {
  int idx = blockIdx.x * 256 + threadIdx.x;
  int i = idx >> 7;
  int c = idx & 127;
  int hd = c >> 5;
  float a = 0.f, ls = 0.f;
#pragma unroll
  for (int s = 0; s < NSEG; ++s) {
    a += pacc[((size_t)s * NTOT + i) * 128 + c];
    ls += plsum[(s * NH + hd) * NTOT + i];
  }
  out[idx] = (ls > 0.f) ? a / ls : 0.f;
}

extern "C" void kernel_launch(void* const* d_in, const int* in_sizes, int n_in,
                              void* d_out, int out_size, void* d_ws,
                              size_t ws_size, hipStream_t stream) {
  const float* X = (const float*)d_in[0];
  const int* adj = (const int*)d_in[1];
  const float* W = (const float*)d_in[2];
  const float* a_src = (const float*)d_in[3];
  const float* a_dst = (const float*)d_in[4];
  float* out = (float*)d_out;

  char* ws = (char*)d_ws;
  float* h = (float*)(ws + 0x0);                             // 4 MB
  unsigned short* panel = (unsigned short*)(ws + 0x400000);  // 2 MB
  float* Sl2 = (float*)(ws + 0x600000);                      // 128 KB
  float* Dt = (float*)(ws + 0x620000);                       // 128 KB
  float* pacc = (float*)(ws + 0x640000);                     // 32 MB
  float* plsum = (float*)(ws + 0x2640000);                   // 1 MB

  k1_project<<<dim3(256), dim3(256), 0, stream>>>(X, W, h, panel);
  k2_scores<<<dim3(32), dim3(256), 0, stream>>>(h, a_src, a_dst, Sl2, Dt);
  k3_attn<<<dim3(128 * NSEG), dim3(256), 0, stream>>>(adj, Sl2, Dt, panel,
                                                      pacc, plsum);
  k4_combine<<<dim3(4096), dim3(256), 0, stream>>>(pacc, plsum, out);
}

// Round 13
// 371.366 us; speedup vs baseline: 1.0004x; 1.0004x over previous
//
#include <hip/hip_runtime.h>
#include <hip/hip_bf16.h>

#define NTOT 8192
#define FIN 128
#define FOUT 32
#define NH 4
#define NSEG 8
#define SEGJ (NTOT / NSEG)  // 1024

#define LOG2E 1.4426950408889634f

typedef __attribute__((ext_vector_type(4))) float f32x4;
typedef __attribute__((ext_vector_type(4))) int i32x4;
typedef __attribute__((ext_vector_type(4))) unsigned int u32x4;
typedef __attribute__((ext_vector_type(8))) __bf16 bf16x8;
typedef unsigned long long u64;
typedef unsigned int u32;

__device__ __forceinline__ unsigned short f2bf(float x) {
  __hip_bfloat16 h = __float2bfloat16(x);
  return *reinterpret_cast<unsigned short*>(&h);
}

__device__ __forceinline__ float fexp2(float y) {
  float p;
  asm("v_exp_f32 %0, %1" : "=v"(p) : "v"(y));
  return p;
}

// ---------------- k1: h = X @ W -> h [N][128] f32, plus B-fragment panels:
// panel[(p*256 + jt)*512 + l*8 + e] (bf16), p = hd*2+half,
//   value = h[node = jt*32 + (l>>4)*8 + e][p*16 + (l&15)]
__global__ __launch_bounds__(256, 2) void k1_project(
    const float* __restrict__ X, const float* __restrict__ W,
    float* __restrict__ h, unsigned short* __restrict__ panel) {
  __shared__ float Xs[32 * 128];
  __shared__ float Ws[32 * 128];
  __shared__ unsigned short Hs[128 * 40];  // [o][node_local], stride 40
  int t = threadIdx.x;
  int nb = blockIdx.x * 32;

  const f32x4* Xg = reinterpret_cast<const f32x4*>(X + (size_t)nb * FIN);
  f32x4* Xs4 = reinterpret_cast<f32x4*>(Xs);
#pragma unroll
  for (int r = 0; r < 4; ++r) Xs4[t + r * 256] = Xg[t + r * 256];

  int ng = t >> 5, oq = t & 31;
  int n0 = ng * 4, o0 = oq * 4;
  f32x4 acc[4];
#pragma unroll
  for (int nn = 0; nn < 4; ++nn) acc[nn] = (f32x4){0.f, 0.f, 0.f, 0.f};

  for (int kp = 0; kp < 4; ++kp) {
    __syncthreads();
#pragma unroll
    for (int r = 0; r < 4; ++r) {
      int q = t + r * 256;
      int flat = q * 4;
      int kk = flat >> 7;
      int c = flat & 127;
      int hdd = c >> 5;
      int oo = c & 31;
      *reinterpret_cast<f32x4*>(&Ws[kk * 128 + c]) =
          *reinterpret_cast<const f32x4*>(W + hdd * (FIN * FOUT) +
                                          (kp * 32 + kk) * FOUT + oo);
    }
    __syncthreads();
#pragma unroll 8
    for (int kk = 0; kk < 32; ++kk) {
      f32x4 wv = *reinterpret_cast<const f32x4*>(&Ws[kk * 128 + o0]);
#pragma unroll
      for (int nn = 0; nn < 4; ++nn)
        acc[nn] += Xs[(n0 + nn) * 128 + kp * 32 + kk] * wv;
    }
  }
#pragma unroll
  for (int nn = 0; nn < 4; ++nn) {
    *reinterpret_cast<f32x4*>(&h[(size_t)(nb + n0 + nn) * 128 + o0]) = acc[nn];
#pragma unroll
    for (int c = 0; c < 4; ++c)
      Hs[(o0 + c) * 40 + (n0 + nn)] = f2bf(acc[nn][c]);
  }
  __syncthreads();
  int jt = blockIdx.x;
#pragma unroll
  for (int it = 0; it < 2; ++it) {
    int item = t + it * 256;
    int p = item >> 6;
    int l = item & 63;
    int o = p * 16 + (l & 15);
    u32x4 v = *reinterpret_cast<const u32x4*>(&Hs[o * 40 + (l >> 4) * 8]);
    *reinterpret_cast<u32x4*>(panel + (size_t)(p * 256 + jt) * 512 + l * 8) = v;
  }
}

// ---------------- k2: per-node scores (x log2e). Sl2 [hd][N]; Dt [jm][hd][64]
__global__ __launch_bounds__(256, 2) void k2_scores(
    const float* __restrict__ h, const float* __restrict__ a_src,
    const float* __restrict__ a_dst, float* __restrict__ Sl2,
    float* __restrict__ Dt) {
  int n = blockIdx.x * 256 + threadIdx.x;
  const f32x4* hv = reinterpret_cast<const f32x4*>(h + (size_t)n * 128);
  const f32x4* as4 = reinterpret_cast<const f32x4*>(a_src);
  const f32x4* ad4 = reinterpret_cast<const f32x4*>(a_dst);
#pragma unroll
  for (int hd = 0; hd < NH; ++hd) {
    f32x4 sa = {0.f, 0.f, 0.f, 0.f}, da = {0.f, 0.f, 0.f, 0.f};
#pragma unroll
    for (int q = 0; q < 8; ++q) {
      f32x4 x = hv[hd * 8 + q];
      sa += x * as4[hd * 8 + q];
      da += x * ad4[hd * 8 + q];
    }
    float s = (sa[0] + sa[1]) + (sa[2] + sa[3]);
    float d = (da[0] + da[1]) + (da[2] + da[3]);
    Sl2[hd * NTOT + n] = s * LOG2E;
    Dt[(n >> 6) * 256 + hd * 64 + (n & 63)] = d * LOG2E;
  }
}

// ---------------- k3: fused adj-read + masked softmax + PV.
// 4 waves/block; wave w = rows [ibase+w*16, +16) x ALL 4 heads (adj read once).
// NSEG=8 -> 4096 waves; waves_per_eu(4,4) pins exactly 4 waves/SIMD resident
// with a 128-VGPR budget (launch_bounds min-waves caused spill in R12).
__global__ __launch_bounds__(256)
__attribute__((amdgpu_waves_per_eu(4, 4))) void k3_attn(
    const int* __restrict__ adj, const float* __restrict__ Sl2,
    const float* __restrict__ Dt, const unsigned short* __restrict__ panel,
    float* __restrict__ pacc, float* __restrict__ plsum) {
  const int N = NTOT;
  int tid = threadIdx.x;
  int w = tid >> 6, l = tid & 63;
  int itile = blockIdx.x >> 3, seg = blockIdx.x & 7;
  int ibase = itile * 64;
  int m = l & 15, g = l >> 4, jc = g * 8;
  int row = ibase + w * 16 + m;
  int seg0 = seg * (SEGJ / 64);  // first 64-j macro of this segment (16/seg)

  float svv[4];
#pragma unroll
  for (int hd = 0; hd < 4; ++hd) svv[hd] = Sl2[hd * N + row];

  const int* adjr = adj + (size_t)row * N + seg * SEGJ + jc;

  f32x4 z4 = {0.f, 0.f, 0.f, 0.f};
  f32x4 c0[4] = {z4, z4, z4, z4}, c1[4] = {z4, z4, z4, z4},
        cs[4] = {z4, z4, z4, z4};
  bf16x8 bones;
  {
    u32 pat = (m == 0) ? 0x3f803f80u : 0u;
    u32x4 tmp = {pat, pat, pat, pat};
    bones = *reinterpret_cast<bf16x8*>(&tmp);
  }

  i32x4 Aa0, Aa1, Aa2, Aa3, Ba0, Ba1, Ba2, Ba3;

  // adj prefetch for macro t_ (pinned so it cannot be sunk)
#define AISS(P, t_)                                            \
  {                                                            \
    int tc_ = (t_) > 15 ? 15 : (t_);                           \
    const int* a_ = adjr + tc_ * 64;                           \
    P##a0 = *reinterpret_cast<const i32x4*>(a_);               \
    P##a1 = *reinterpret_cast<const i32x4*>(a_ + 4);           \
    P##a2 = *reinterpret_cast<const i32x4*>(a_ + 32);          \
    P##a3 = *reinterpret_cast<const i32x4*>(a_ + 36);          \
  }                                                            \
  __builtin_amdgcn_sched_barrier(0);

  // masked A-frag: y = LeakyReLU(s+d)*log2e, gated to -1e9 by adj, exp2
#define AFSEL(AF, AV0, AV1, DA, DB, SV)                                  \
  {                                                                      \
    f32x4 xa_ = (DA) + (SV);                                             \
    f32x4 xb_ = (DB) + (SV);                                             \
    f32x4 ya_ = __builtin_elementwise_max(xa_, 0.2f * xa_);              \
    f32x4 yb_ = __builtin_elementwise_max(xb_, 0.2f * xb_);              \
    _Pragma("unroll") for (int e = 0; e < 4; ++e) {                      \
      float y_ = ((AV0)[e] != 0) ? ya_[e] : -1e9f;                       \
      AF[e] = (__bf16)fexp2(y_);                                         \
    }                                                                    \
    _Pragma("unroll") for (int e = 0; e < 4; ++e) {                      \
      float y_ = ((AV1)[e] != 0) ? yb_[e] : -1e9f;                       \
      AF[e + 4] = (__bf16)fexp2(y_);                                     \
    }                                                                    \
  }

#define MFM(AF, B, ACC) \
  ACC = __builtin_amdgcn_mfma_f32_16x16x32_bf16(AF, B, ACC, 0, 0, 0);

  // full macro: 4 heads x (2 k-halves x 3 MFMA)
#define MATHM(P, t_)                                                      \
  {                                                                       \
    int jm_ = seg0 + (t_);                                                \
    const float* db_ = Dt + (size_t)jm_ * 256;                            \
    const unsigned short* pb_ =                                           \
        panel + (size_t)(seg * (SEGJ / 32) + (t_)*2) * 512 + l * 8;       \
    _Pragma("unroll") for (int hd = 0; hd < 4; ++hd) {                    \
      f32x4 d0 = *(const f32x4*)(db_ + hd * 64 + jc);                     \
      f32x4 d1 = *(const f32x4*)(db_ + hd * 64 + jc + 4);                 \
      f32x4 d2 = *(const f32x4*)(db_ + hd * 64 + 32 + jc);                \
      f32x4 d3 = *(const f32x4*)(db_ + hd * 64 + 32 + jc + 4);            \
      const unsigned short* p0_ = pb_ + (size_t)(hd * 2) * 131072;        \
      const unsigned short* p1_ = pb_ + (size_t)(hd * 2 + 1) * 131072;    \
      bf16x8 B0a = *(const bf16x8*)(p0_);                                 \
      bf16x8 B1a = *(const bf16x8*)(p1_);                                 \
      bf16x8 B0b = *(const bf16x8*)(p0_ + 512);                           \
      bf16x8 B1b = *(const bf16x8*)(p1_ + 512);                           \
      float sv_ = svv[hd];                                                \
      bf16x8 af_;                                                         \
      AFSEL(af_, P##a0, P##a1, d0, d1, sv_)                               \
      MFM(af_, B0a, c0[hd]) MFM(af_, B1a, c1[hd]) MFM(af_, bones, cs[hd]) \
      AFSEL(af_, P##a2, P##a3, d2, d3, sv_)                               \
      MFM(af_, B0b, c0[hd]) MFM(af_, B1b, c1[hd]) MFM(af_, bones, cs[hd]) \
    }                                                                     \
  }

  AISS(A, 0)
  AISS(B, 1)
#pragma unroll 1
  for (int tt = 0; tt < 8; ++tt) {
    MATHM(A, 2 * tt)
    AISS(A, 2 * tt + 2)
    MATHM(B, 2 * tt + 1)
    AISS(B, 2 * tt + 3)
  }
#undef AISS
#undef AFSEL
#undef MFM
#undef MATHM

  // epilogue: D layout col=lane&15 (o), row=(lane>>4)*4+reg (i)
#pragma unroll
  for (int hd = 0; hd < 4; ++hd) {
    int rb = ibase + w * 16 + g * 4;
    if (m == 0) {
#pragma unroll
      for (int r = 0; r < 4; ++r)
        plsum[(seg * NH + hd) * N + rb + r] = cs[hd][r];
    }
#pragma unroll
    for (int r = 0; r < 4; ++r) {
      int rowr = rb + r;
      pacc[((size_t)seg * N + rowr) * 128 + hd * 32 + m] = c0[hd][r];
      pacc[((size_t)seg * N + rowr) * 128 + hd * 32 + 16 + m] = c1[hd][r];
    }
  }
}

// ---------------- k4: combine segments + normalize
__global__ __launch_bounds__(256, 2) void k4_combine(
    const float* __restrict__ pacc, const float* __restrict__ plsum,
    float* __restrict__ out) {
  int idx = blockIdx.x * 256 + threadIdx.x;
  int i = idx >> 7;
  int c = idx & 127;
  int hd = c >> 5;
  float a = 0.f, ls = 0.f;
#pragma unroll
  for (int s = 0; s < NSEG; ++s) {
    a += pacc[((size_t)s * NTOT + i) * 128 + c];
    ls += plsum[(s * NH + hd) * NTOT + i];
  }
  out[idx] = (ls > 0.f) ? a / ls : 0.f;
}

extern "C" void kernel_launch(void* const* d_in, const int* in_sizes, int n_in,
                              void* d_out, int out_size, void* d_ws,
                              size_t ws_size, hipStream_t stream) {
  const float* X = (const float*)d_in[0];
  const int* adj = (const int*)d_in[1];
  const float* W = (const float*)d_in[2];
  const float* a_src = (const float*)d_in[3];
  const float* a_dst = (const float*)d_in[4];
  float* out = (float*)d_out;

  char* ws = (char*)d_ws;
  float* h = (float*)(ws + 0x0);                             // 4 MB
  unsigned short* panel = (unsigned short*)(ws + 0x400000);  // 2 MB
  float* Sl2 = (float*)(ws + 0x600000);                      // 128 KB
  float* Dt = (float*)(ws + 0x620000);                       // 128 KB
  float* pacc = (float*)(ws + 0x640000);                     // 32 MB
  float* plsum = (float*)(ws + 0x2640000);                   // 1 MB

  k1_project<<<dim3(256), dim3(256), 0, stream>>>(X, W, h, panel);
  k2_scores<<<dim3(32), dim3(256), 0, stream>>>(h, a_src, a_dst, Sl2, Dt);
  k3_attn<<<dim3(128 * NSEG), dim3(256), 0, stream>>>(adj, Sl2, Dt, panel,
                                                      pacc, plsum);
  k4_combine<<<dim3(4096), dim3(256), 0, stream>>>(pacc, plsum, out);
}

// Round 14
// 169.435 us; speedup vs baseline: 2.1926x; 2.1918x over previous
//
#include <hip/hip_runtime.h>
#include <hip/hip_bf16.h>

#define NTOT 8192
#define FIN 128
#define FOUT 32
#define NH 4
#define NSEG 8
#define SEGJ (NTOT / NSEG)  // 1024

#define LOG2E 1.4426950408889634f

typedef __attribute__((ext_vector_type(4))) float f32x4;
typedef __attribute__((ext_vector_type(4))) int i32x4;
typedef __attribute__((ext_vector_type(4))) unsigned int u32x4;
typedef __attribute__((ext_vector_type(8))) __bf16 bf16x8;
typedef unsigned long long u64;
typedef unsigned int u32;

__device__ __forceinline__ unsigned short f2bf(float x) {
  __hip_bfloat16 h = __float2bfloat16(x);
  return *reinterpret_cast<unsigned short*>(&h);
}

__device__ __forceinline__ float fexp2(float y) {
  float p;
  asm("v_exp_f32 %0, %1" : "=v"(p) : "v"(y));
  return p;
}

// ---------------- k1: h = X @ W -> h [N][128] f32, plus B-fragment panels:
// panel[(p*256 + jt)*512 + l*8 + e] (bf16), p = hd*2+half,
//   value = h[node = jt*32 + (l>>4)*8 + e][p*16 + (l&15)]
__global__ __launch_bounds__(256, 2) void k1_project(
    const float* __restrict__ X, const float* __restrict__ W,
    float* __restrict__ h, unsigned short* __restrict__ panel) {
  __shared__ float Xs[32 * 128];
  __shared__ float Ws[32 * 128];
  __shared__ unsigned short Hs[128 * 40];  // [o][node_local], stride 40
  int t = threadIdx.x;
  int nb = blockIdx.x * 32;

  const f32x4* Xg = reinterpret_cast<const f32x4*>(X + (size_t)nb * FIN);
  f32x4* Xs4 = reinterpret_cast<f32x4*>(Xs);
#pragma unroll
  for (int r = 0; r < 4; ++r) Xs4[t + r * 256] = Xg[t + r * 256];

  int ng = t >> 5, oq = t & 31;
  int n0 = ng * 4, o0 = oq * 4;
  f32x4 acc[4];
#pragma unroll
  for (int nn = 0; nn < 4; ++nn) acc[nn] = (f32x4){0.f, 0.f, 0.f, 0.f};

  for (int kp = 0; kp < 4; ++kp) {
    __syncthreads();
#pragma unroll
    for (int r = 0; r < 4; ++r) {
      int q = t + r * 256;
      int flat = q * 4;
      int kk = flat >> 7;
      int c = flat & 127;
      int hdd = c >> 5;
      int oo = c & 31;
      *reinterpret_cast<f32x4*>(&Ws[kk * 128 + c]) =
          *reinterpret_cast<const f32x4*>(W + hdd * (FIN * FOUT) +
                                          (kp * 32 + kk) * FOUT + oo);
    }
    __syncthreads();
#pragma unroll 8
    for (int kk = 0; kk < 32; ++kk) {
      f32x4 wv = *reinterpret_cast<const f32x4*>(&Ws[kk * 128 + o0]);
#pragma unroll
      for (int nn = 0; nn < 4; ++nn)
        acc[nn] += Xs[(n0 + nn) * 128 + kp * 32 + kk] * wv;
    }
  }
#pragma unroll
  for (int nn = 0; nn < 4; ++nn) {
    *reinterpret_cast<f32x4*>(&h[(size_t)(nb + n0 + nn) * 128 + o0]) = acc[nn];
#pragma unroll
    for (int c = 0; c < 4; ++c)
      Hs[(o0 + c) * 40 + (n0 + nn)] = f2bf(acc[nn][c]);
  }
  __syncthreads();
  int jt = blockIdx.x;
#pragma unroll
  for (int it = 0; it < 2; ++it) {
    int item = t + it * 256;
    int p = item >> 6;
    int l = item & 63;
    int o = p * 16 + (l & 15);
    u32x4 v = *reinterpret_cast<const u32x4*>(&Hs[o * 40 + (l >> 4) * 8]);
    *reinterpret_cast<u32x4*>(panel + (size_t)(p * 256 + jt) * 512 + l * 8) = v;
  }
}

// ---------------- k2: per-node scores (x log2e). Sl2 [hd][N]; Dt [jm][hd][64]
__global__ __launch_bounds__(256, 2) void k2_scores(
    const float* __restrict__ h, const float* __restrict__ a_src,
    const float* __restrict__ a_dst, float* __restrict__ Sl2,
    float* __restrict__ Dt) {
  int n = blockIdx.x * 256 + threadIdx.x;
  const f32x4* hv = reinterpret_cast<const f32x4*>(h + (size_t)n * 128);
  const f32x4* as4 = reinterpret_cast<const f32x4*>(a_src);
  const f32x4* ad4 = reinterpret_cast<const f32x4*>(a_dst);
#pragma unroll
  for (int hd = 0; hd < NH; ++hd) {
    f32x4 sa = {0.f, 0.f, 0.f, 0.f}, da = {0.f, 0.f, 0.f, 0.f};
#pragma unroll
    for (int q = 0; q < 8; ++q) {
      f32x4 x = hv[hd * 8 + q];
      sa += x * as4[hd * 8 + q];
      da += x * ad4[hd * 8 + q];
    }
    float s = (sa[0] + sa[1]) + (sa[2] + sa[3]);
    float d = (da[0] + da[1]) + (da[2] + da[3]);
    Sl2[hd * NTOT + n] = s * LOG2E;
    Dt[(n >> 6) * 256 + hd * 64 + (n & 63)] = d * LOG2E;
  }
}

// ---------------- k3: fused adj-read + masked softmax + PV.
// 4 waves/block; wave w = rows [ibase+w*16, +16) x ALL 4 heads (adj read once).
// NSEG=8 -> 4096 waves (4/SIMD). waves_per_eu(2) = min-only: same allocation
// regime as R11's proven 88-VGPR no-spill build; 88 <= 128 bucket, so HW runs
// 4 waves/SIMD from the grid. (Any forced min>=4 made the allocator clamp to
// 64 VGPR and spill ~500 MB of scratch — R12/R13.)
__global__ __launch_bounds__(256)
__attribute__((amdgpu_waves_per_eu(2))) void k3_attn(
    const int* __restrict__ adj, const float* __restrict__ Sl2,
    const float* __restrict__ Dt, const unsigned short* __restrict__ panel,
    float* __restrict__ pacc, float* __restrict__ plsum) {
  const int N = NTOT;
  int tid = threadIdx.x;
  int w = tid >> 6, l = tid & 63;
  int itile = blockIdx.x >> 3, seg = blockIdx.x & 7;
  int ibase = itile * 64;
  int m = l & 15, g = l >> 4, jc = g * 8;
  int row = ibase + w * 16 + m;
  int seg0 = seg * (SEGJ / 64);  // first 64-j macro of this segment (16/seg)

  float svv[4];
#pragma unroll
  for (int hd = 0; hd < 4; ++hd) svv[hd] = Sl2[hd * N + row];

  const int* adjr = adj + (size_t)row * N + seg * SEGJ + jc;

  f32x4 z4 = {0.f, 0.f, 0.f, 0.f};
  f32x4 c0[4] = {z4, z4, z4, z4}, c1[4] = {z4, z4, z4, z4},
        cs[4] = {z4, z4, z4, z4};
  bf16x8 bones;
  {
    u32 pat = (m == 0) ? 0x3f803f80u : 0u;
    u32x4 tmp = {pat, pat, pat, pat};
    bones = *reinterpret_cast<bf16x8*>(&tmp);
  }

  i32x4 Aa0, Aa1, Aa2, Aa3, Ba0, Ba1, Ba2, Ba3;

  // adj prefetch for macro t_ (pinned so it cannot be sunk)
#define AISS(P, t_)                                            \
  {                                                            \
    int tc_ = (t_) > 15 ? 15 : (t_);                           \
    const int* a_ = adjr + tc_ * 64;                           \
    P##a0 = *reinterpret_cast<const i32x4*>(a_);               \
    P##a1 = *reinterpret_cast<const i32x4*>(a_ + 4);           \
    P##a2 = *reinterpret_cast<const i32x4*>(a_ + 32);          \
    P##a3 = *reinterpret_cast<const i32x4*>(a_ + 36);          \
  }                                                            \
  __builtin_amdgcn_sched_barrier(0);

  // masked A-frag: y = LeakyReLU(s+d)*log2e, gated to -1e9 by adj, exp2
#define AFSEL(AF, AV0, AV1, DA, DB, SV)                                  \
  {                                                                      \
    f32x4 xa_ = (DA) + (SV);                                             \
    f32x4 xb_ = (DB) + (SV);                                             \
    f32x4 ya_ = __builtin_elementwise_max(xa_, 0.2f * xa_);              \
    f32x4 yb_ = __builtin_elementwise_max(xb_, 0.2f * xb_);              \
    _Pragma("unroll") for (int e = 0; e < 4; ++e) {                      \
      float y_ = ((AV0)[e] != 0) ? ya_[e] : -1e9f;                       \
      AF[e] = (__bf16)fexp2(y_);                                         \
    }                                                                    \
    _Pragma("unroll") for (int e = 0; e < 4; ++e) {                      \
      float y_ = ((AV1)[e] != 0) ? yb_[e] : -1e9f;                       \
      AF[e + 4] = (__bf16)fexp2(y_);                                     \
    }                                                                    \
  }

#define MFM(AF, B, ACC) \
  ACC = __builtin_amdgcn_mfma_f32_16x16x32_bf16(AF, B, ACC, 0, 0, 0);

  // full macro: 4 heads x (2 k-halves x 3 MFMA)
#define MATHM(P, t_)                                                      \
  {                                                                       \
    int jm_ = seg0 + (t_);                                                \
    const float* db_ = Dt + (size_t)jm_ * 256;                            \
    const unsigned short* pb_ =                                           \
        panel + (size_t)(seg * (SEGJ / 32) + (t_)*2) * 512 + l * 8;       \
    _Pragma("unroll") for (int hd = 0; hd < 4; ++hd) {                    \
      f32x4 d0 = *(const f32x4*)(db_ + hd * 64 + jc);                     \
      f32x4 d1 = *(const f32x4*)(db_ + hd * 64 + jc + 4);                 \
      f32x4 d2 = *(const f32x4*)(db_ + hd * 64 + 32 + jc);                \
      f32x4 d3 = *(const f32x4*)(db_ + hd * 64 + 32 + jc + 4);            \
      const unsigned short* p0_ = pb_ + (size_t)(hd * 2) * 131072;        \
      const unsigned short* p1_ = pb_ + (size_t)(hd * 2 + 1) * 131072;    \
      bf16x8 B0a = *(const bf16x8*)(p0_);                                 \
      bf16x8 B1a = *(const bf16x8*)(p1_);                                 \
      bf16x8 B0b = *(const bf16x8*)(p0_ + 512);                           \
      bf16x8 B1b = *(const bf16x8*)(p1_ + 512);                           \
      float sv_ = svv[hd];                                                \
      bf16x8 af_;                                                         \
      AFSEL(af_, P##a0, P##a1, d0, d1, sv_)                               \
      MFM(af_, B0a, c0[hd]) MFM(af_, B1a, c1[hd]) MFM(af_, bones, cs[hd]) \
      AFSEL(af_, P##a2, P##a3, d2, d3, sv_)                               \
      MFM(af_, B0b, c0[hd]) MFM(af_, B1b, c1[hd]) MFM(af_, bones, cs[hd]) \
    }                                                                     \
  }

  AISS(A, 0)
  AISS(B, 1)
#pragma unroll 1
  for (int tt = 0; tt < 8; ++tt) {
    MATHM(A, 2 * tt)
    AISS(A, 2 * tt + 2)
    MATHM(B, 2 * tt + 1)
    AISS(B, 2 * tt + 3)
  }
#undef AISS
#undef AFSEL
#undef MFM
#undef MATHM

  // epilogue: D layout col=lane&15 (o), row=(lane>>4)*4+reg (i)
#pragma unroll
  for (int hd = 0; hd < 4; ++hd) {
    int rb = ibase + w * 16 + g * 4;
    if (m == 0) {
#pragma unroll
      for (int r = 0; r < 4; ++r)
        plsum[(seg * NH + hd) * N + rb + r] = cs[hd][r];
    }
#pragma unroll
    for (int r = 0; r < 4; ++r) {
      int rowr = rb + r;
      pacc[((size_t)seg * N + rowr) * 128 + hd * 32 + m] = c0[hd][r];
      pacc[((size_t)seg * N + rowr) * 128 + hd * 32 + 16 + m] = c1[hd][r];
    }
  }
}

// ---------------- k4: combine segments + normalize
__global__ __launch_bounds__(256, 2) void k4_combine(
    const float* __restrict__ pacc, const float* __restrict__ plsum,
    float* __restrict__ out) {
  int idx = blockIdx.x * 256 + threadIdx.x;
  int i = idx >> 7;
  int c = idx & 127;
  int hd = c >> 5;
  float a = 0.f, ls = 0.f;
#pragma unroll
  for (int s = 0; s < NSEG; ++s) {
    a += pacc[((size_t)s * NTOT + i) * 128 + c];
    ls += plsum[(s * NH + hd) * NTOT + i];
  }
  out[idx] = (ls > 0.f) ? a / ls : 0.f;
}

extern "C" void kernel_launch(void* const* d_in, const int* in_sizes, int n_in,
                              void* d_out, int out_size, void* d_ws,
                              size_t ws_size, hipStream_t stream) {
  const float* X = (const float*)d_in[0];
  const int* adj = (const int*)d_in[1];
  const float* W = (const float*)d_in[2];
  const float* a_src = (const float*)d_in[3];
  const float* a_dst = (const float*)d_in[4];
  float* out = (float*)d_out;

  char* ws = (char*)d_ws;
  float* h = (float*)(ws + 0x0);                             // 4 MB
  unsigned short* panel = (unsigned short*)(ws + 0x400000);  // 2 MB
  float* Sl2 = (float*)(ws + 0x600000);                      // 128 KB
  float* Dt = (float*)(ws + 0x620000);                       // 128 KB
  float* pacc = (float*)(ws + 0x640000);                     // 32 MB
  float* plsum = (float*)(ws + 0x2640000);                   // 1 MB

  k1_project<<<dim3(256), dim3(256), 0, stream>>>(X, W, h, panel);
  k2_scores<<<dim3(32), dim3(256), 0, stream>>>(h, a_src, a_dst, Sl2, Dt);
  k3_attn<<<dim3(128 * NSEG), dim3(256), 0, stream>>>(adj, Sl2, Dt, panel,
                                                      pacc, plsum);
  k4_combine<<<dim3(4096), dim3(256), 0, stream>>>(pacc, plsum, out);
}